// Round 13
// baseline (1015.408 us; speedup 1.0000x reference)
//
#include <hip/hip_runtime.h>
#include <hip/hip_fp16.h>

#define NNODES 500000
#define NEDGES 16000000
#define NBLK 1024           // histogram/scatter blocks
#define EPB (NEDGES / NBLK) // 15625 edges per block (exact)
#define BSH 11              // bucket shift: 2048 nodes per bucket
#define BSZ 2048
#define NBKT 245            // ceil(NNODES / 2048)
#define BDIM 256            // padded bucket dimension (245 <= 256)
#define CHUNK 2048          // staged-scatter chunk (8 chunks per block)
#define KPC (CHUNK / 256)   // records per thread per chunk = 8
#define CTH 1024            // consumer threads per block

typedef unsigned long long u64;
typedef unsigned int u32;
typedef unsigned short u16;

// ---------------- helpers ----------------

__device__ __forceinline__ u32 fmap_ord(float x) {
    u32 u = __float_as_uint(x);
    return (u & 0x80000000u) ? ~u : (u | 0x80000000u);
}
__device__ __forceinline__ float funmap_ord(u32 u) {
    u32 bits = (u & 0x80000000u) ? (u ^ 0x80000000u) : ~u;
    return __uint_as_float(bits);
}

// block reduce for 256-thread blocks
__device__ __forceinline__ void block_reduce_atomic4(float v0, float v1, float v2, float v3,
                                                     float* dst) {
    for (int off = 32; off > 0; off >>= 1) {
        v0 += __shfl_down(v0, off, 64);
        v1 += __shfl_down(v1, off, 64);
        v2 += __shfl_down(v2, off, 64);
        v3 += __shfl_down(v3, off, 64);
    }
    __shared__ float red[4][4];
    int lane = threadIdx.x & 63, wid = threadIdx.x >> 6;
    if (lane == 0) { red[wid][0] = v0; red[wid][1] = v1; red[wid][2] = v2; red[wid][3] = v3; }
    __syncthreads();
    if (threadIdx.x < 4) {
        float t = red[0][threadIdx.x] + red[1][threadIdx.x] + red[2][threadIdx.x] + red[3][threadIdx.x];
        unsafeAtomicAdd(&dst[threadIdx.x], t);
    }
}

// block reduce for 1024-thread blocks (16 waves)
__device__ __forceinline__ void block_reduce_atomic4_w16(float v0, float v1, float v2, float v3,
                                                         float* dst) {
    for (int off = 32; off > 0; off >>= 1) {
        v0 += __shfl_down(v0, off, 64);
        v1 += __shfl_down(v1, off, 64);
        v2 += __shfl_down(v2, off, 64);
        v3 += __shfl_down(v3, off, 64);
    }
    __shared__ float red[16][4];
    int lane = threadIdx.x & 63, wid = threadIdx.x >> 6;
    if (lane == 0) { red[wid][0] = v0; red[wid][1] = v1; red[wid][2] = v2; red[wid][3] = v3; }
    __syncthreads();
    if (threadIdx.x < 4) {
        float t = 0.f;
        #pragma unroll
        for (int w = 0; w < 16; ++w) t += red[w][threadIdx.x];
        unsafeAtomicAdd(&dst[threadIdx.x], t);
    }
}

// ---------------- shared kernels ----------------

__global__ __launch_bounds__(64) void k_zero_accum(float* accum) {
    if (threadIdx.x < 16) accum[threadIdx.x] = 0.f;
}

// per-node linears: q, k, v
__global__ __launch_bounds__(256) void k_node_prep(
    const float* __restrict__ x,
    const float* __restrict__ Wq, const float* __restrict__ bq,
    const float* __restrict__ Wk, const float* __restrict__ bk,
    const float* __restrict__ Wv, const float* __restrict__ bv,
    float2* __restrict__ q, float4* __restrict__ kv) {
    int i = blockIdx.x * blockDim.x + threadIdx.x;
    if (i >= NNODES) return;
    float2 xv = ((const float2*)x)[i];
    float q0 = fmaf(Wq[0], xv.x, fmaf(Wq[1], xv.y, bq[0]));
    float q1 = fmaf(Wq[2], xv.x, fmaf(Wq[3], xv.y, bq[1]));
    float k0 = fmaf(Wk[0], xv.x, fmaf(Wk[1], xv.y, bk[0]));
    float k1 = fmaf(Wk[2], xv.x, fmaf(Wk[3], xv.y, bk[1]));
    float v0 = fmaf(Wv[0], xv.x, fmaf(Wv[1], xv.y, bv[0]));
    float v1 = fmaf(Wv[2], xv.x, fmaf(Wv[3], xv.y, bv[1]));
    q[i] = make_float2(q0, q1);
    kv[i] = make_float4(k0, k1, v0, v1);
}

// 1-thread: layernorm scale/shift
__global__ void k_ln_final(const float* __restrict__ gamma, const float* __restrict__ beta,
                           float* __restrict__ accum) {
    float n = (float)NNODES;
    float mu0 = accum[0] / n, mu1 = accum[1] / n;
    float var0 = accum[2] / n - mu0 * mu0;
    float var1 = accum[3] / n - mu1 * mu1;
    float sc0 = gamma[0] * rsqrtf(var0 + 1e-5f);
    float sc1 = gamma[1] * rsqrtf(var1 + 1e-5f);
    accum[8] = sc0;
    accum[9] = sc1;
    accum[10] = beta[0] - mu0 * sc0;
    accum[11] = beta[1] - mu1 * sc1;
}

// per-node: normalized h -> exp (f32 p-plane); reduce column sums
__global__ __launch_bounds__(256) void k_softmax(
    const float2* __restrict__ h, float2* __restrict__ pp, float* __restrict__ accum) {
    int i = blockIdx.x * blockDim.x + threadIdx.x;
    float p0 = 0.f, p1 = 0.f;
    if (i < NNODES) {
        float sc0 = accum[8], sc1 = accum[9], sh0 = accum[10], sh1 = accum[11];
        float2 hv = h[i];
        p0 = __expf(fmaf(hv.x, sc0, sh0));
        p1 = __expf(fmaf(hv.y, sc1, sh1));
        pp[i] = make_float2(p0, p1);
    }
    block_reduce_atomic4(p0, p1, 0.f, 0.f, accum + 4);
}

// 1-thread: softmax denominators -> reciprocals
__global__ void k_sm_final(float* __restrict__ accum) {
    accum[12] = 1.f / accum[4];
    accum[13] = 1.f / accum[5];
}

// ---------------- sort infrastructure ----------------

// per-block LDS histogram of dst buckets -> counts matrix M[blk][bucket]
__global__ __launch_bounds__(256) void k_hist(const int2* __restrict__ dst2, u32* __restrict__ M) {
    __shared__ u32 hist[BDIM];
    if (threadIdx.x < BDIM) hist[threadIdx.x] = 0u;
    __syncthreads();
    int beg = blockIdx.x * EPB, end = beg + EPB;
    #pragma unroll 4
    for (int e = beg + threadIdx.x; e < end; e += 256)
        atomicAdd(&hist[dst2[e].y >> BSH], 1u);
    __syncthreads();
    u32* row = M + (size_t)blockIdx.x * BDIM;
    if (threadIdx.x < BDIM) row[threadIdx.x] = hist[threadIdx.x];
}

// per bucket: column prefix over blocks (in place), bucket totals out
__global__ __launch_bounds__(256) void k_bucket_prefix(u32* __restrict__ M, u32* __restrict__ bucketTotal) {
    __shared__ u32 col[NBLK];
    int b = blockIdx.x;
    for (int j = threadIdx.x; j < NBLK; j += 256) col[j] = M[(size_t)j * BDIM + b];
    __syncthreads();
    if (threadIdx.x == 0) {
        u32 run = 0;
        for (int j = 0; j < NBLK; ++j) { u32 c = col[j]; col[j] = run; run += c; }
        bucketTotal[b] = run;
    }
    __syncthreads();
    for (int j = threadIdx.x; j < NBLK; j += 256) M[(size_t)j * BDIM + b] = col[j];
}

// exclusive scan of bucket totals (serial in LDS)
__global__ __launch_bounds__(256) void k_scan_serial(const u32* __restrict__ bucketTotal,
                                                     u32* __restrict__ bucketBase) {
    __shared__ u32 t[BDIM];
    __shared__ u32 o[BDIM + 1];
    if (threadIdx.x < BDIM) t[threadIdx.x] = bucketTotal[threadIdx.x];
    __syncthreads();
    if (threadIdx.x == 0) {
        u32 run = 0;
        for (int j = 0; j < BDIM; ++j) { o[j] = run; run += t[j]; }
        o[BDIM] = run;
    }
    __syncthreads();
    for (int j = threadIdx.x; j < BDIM + 1; j += 256) bucketBase[j] = o[j];
}

// ---------------- fused scatter: edge math + dual record streams ----------------
// R1 = [lisi | a | a*(v0+e0) | a*(v1+e1)] (16B)  -- pass-1 payload (exact f32)
// R2 = [lisi | pk_f16(c0,c1)]             (8B)   -- pass-2 payload
// lisi = si | (di&2047)<<19  (si<2^19, li<2^11)

__global__ __launch_bounds__(256) void k_scatter_fused(
    const int2* __restrict__ src2, const int2* __restrict__ dst2,
    const float4* __restrict__ ea4, const float* __restrict__ We,
    const float2* __restrict__ qp, const float4* __restrict__ kvp,
    const u32* __restrict__ M, const u32* __restrict__ bucketBase,
    float4* __restrict__ R1, uint2* __restrict__ R2) {
    __shared__ u32 hist[BDIM];
    __shared__ u32 lbase[BDIM];
    __shared__ u32 gcur[BDIM];
    __shared__ u32 wsum[4];
    __shared__ float4 buf1[CHUNK];
    __shared__ uint2 buf2[CHUNK];
    __shared__ u16 bkt[CHUNK];

    const u32* row = M + (size_t)blockIdx.x * BDIM;
    if (threadIdx.x < BDIM) gcur[threadIdx.x] = row[threadIdx.x] + bucketBase[threadIdx.x];
    float we00 = We[0], we01 = We[1], we10 = We[2], we11 = We[3];
    int beg = blockIdx.x * EPB;
    int lane = threadIdx.x & 63, wid = threadIdx.x >> 6;

    for (int c0 = 0; c0 < EPB; c0 += CHUNK) {
        int cn = min(CHUNK, EPB - c0);
        if (threadIdx.x < BDIM) hist[threadIdx.x] = 0u;
        __syncthreads();

        // load chunk, gather q/kv, compute edge terms, count + rank via LDS atomics
        float4 r1[KPC]; uint2 r2[KPC]; u32 bks[KPC]; u32 rnk[KPC]; bool val[KPC];
        #pragma unroll
        for (int k = 0; k < KPC; ++k) {
            int tt = k * 256 + threadIdx.x;
            val[k] = tt < cn;
            if (val[k]) {
                int e = beg + c0 + tt;
                int si = src2[e].y;                 // edge_index[0, 2e+1]
                int di = dst2[e].y;                 // edge_index[1, 2e+1]
                float4 eav = ea4[e];                // rows 2e (clause), 2e+1 (attn)
                float e0 = fmaf(we00, eav.z, we01 * eav.w);
                float e1 = fmaf(we10, eav.z, we11 * eav.w);
                float4 kvv = kvp[si];
                float2 qv = qp[di];
                float alpha = fmaf(qv.x, kvv.x + e0, qv.y * (kvv.y + e1)) * 0.70710678118654752f;
                float a = __expf(alpha);
                float am0 = a * (kvv.z + e0);
                float am1 = a * (kvv.w + e1);
                u32 b = (u32)di >> BSH;
                u32 lisi = (u32)si | ((u32)(di & (BSZ - 1)) << 19);
                __half2 hc = __floats2half2_rn(eav.x, eav.y);
                r1[k] = make_float4(__uint_as_float(lisi), a, am0, am1);
                r2[k] = make_uint2(lisi, *(u32*)&hc);
                bks[k] = b;
                rnk[k] = atomicAdd(&hist[b], 1u);
            }
        }
        __syncthreads();

        // exclusive scan of hist[0..BDIM): one entry per thread
        u32 s = hist[threadIdx.x];
        u32 inc = s;
        #pragma unroll
        for (int d = 1; d < 64; d <<= 1) {
            u32 v = __shfl_up(inc, d, 64);
            if (lane >= d) inc += v;
        }
        if (lane == 63) wsum[wid] = inc;
        __syncthreads();
        u32 woff = 0;
        for (int w = 0; w < wid; ++w) woff += wsum[w];
        lbase[threadIdx.x] = woff + inc - s;
        __syncthreads();

        // bucket-sorted scatter into LDS (shared rank for both streams)
        #pragma unroll
        for (int k = 0; k < KPC; ++k) {
            if (val[k]) {
                u32 p = lbase[bks[k]] + rnk[k];
                buf1[p] = r1[k];
                buf2[p] = r2[k];
                bkt[p] = (u16)bks[k];
            }
        }
        __syncthreads();

        // coalesced flush: consecutive j -> consecutive global addresses per run
        for (int j = threadIdx.x; j < cn; j += 256) {
            u32 b = bkt[j];
            u32 off = gcur[b] + (u32)j - lbase[b];
            R1[(size_t)off] = buf1[j];
            R2[(size_t)off] = buf2[j];
        }
        __syncthreads();

        // advance global cursors
        if (threadIdx.x < BDIM) gcur[threadIdx.x] += hist[threadIdx.x];
        __syncthreads();
    }
}

// edge pass 1: pure stream + per-bucket LDS accumulate, fused conv-finalize + LN sums
__global__ __launch_bounds__(CTH) void k_attn16(
    const float4* __restrict__ R1,
    const u32* __restrict__ bucketBase, const u32* __restrict__ bucketTotal,
    const float* __restrict__ x,
    const float* __restrict__ Wskip, const float* __restrict__ bskip,
    float2* __restrict__ h, float* __restrict__ accum) {
    __shared__ float sA[BSZ], m0A[BSZ], m1A[BSZ];
    int b = blockIdx.x, base = b << BSH;
    for (int j = threadIdx.x; j < BSZ; j += CTH) {
        sA[j] = 0.f; m0A[j] = 0.f; m1A[j] = 0.f;
    }
    __syncthreads();
    int beg = bucketBase[b], end = beg + bucketTotal[b];
    for (int idx = beg + threadIdx.x; idx < end; idx += CTH) {
        float4 r = R1[idx];
        int li = (int)(__float_as_uint(r.x) >> 19);
        atomicAdd(&sA[li], r.y);
        atomicAdd(&m0A[li], r.z);
        atomicAdd(&m1A[li], r.w);
    }
    __syncthreads();
    float r0 = 0.f, r1 = 0.f, r2 = 0.f, r3 = 0.f;
    float w00 = Wskip[0], w01 = Wskip[1], w10 = Wskip[2], w11 = Wskip[3];
    float c0 = bskip[0], c1 = bskip[1];
    for (int j = threadIdx.x; j < BSZ; j += CTH) {
        int i = base + j;
        if (i < NNODES) {
            float2 xv = ((const float2*)x)[i];
            float s = sA[j];
            float inv = s > 0.f ? 1.f / s : 0.f;
            float h0 = fmaf(m0A[j], inv, fmaf(w00, xv.x, fmaf(w01, xv.y, c0)));
            float h1 = fmaf(m1A[j], inv, fmaf(w10, xv.x, fmaf(w11, xv.y, c1)));
            h[i] = make_float2(h0, h1);
            r0 += h0; r1 += h1; r2 += h0 * h0; r3 += h1 * h1;
        }
    }
    block_reduce_atomic4_w16(r0, r1, r2, r3, accum);
}

// edge pass 2: stream R2, per-bucket LDS max (skip masked dst), fused final output
__global__ __launch_bounds__(CTH) void k_nmax16(
    const uint2* __restrict__ R2,
    const u32* __restrict__ bucketBase, const u32* __restrict__ bucketTotal,
    const float2* __restrict__ pp, const float* __restrict__ accum,
    const float* __restrict__ Wf, const float* __restrict__ bf,
    const float* __restrict__ mask, float* __restrict__ out) {
    __shared__ u32 mxA[BSZ];
    __shared__ float maskT[BSZ];
    int b = blockIdx.x, base = b << BSH;
    for (int j = threadIdx.x; j < BSZ; j += CTH) {
        mxA[j] = 0u;
        int i = base + j;
        maskT[j] = (i < NNODES) ? mask[i] : 0.f;
    }
    __syncthreads();
    float inv0 = accum[12], inv1 = accum[13];
    int beg = bucketBase[b], end = beg + bucketTotal[b];
    for (int idx = beg + threadIdx.x; idx < end; idx += CTH) {
        uint2 r = R2[idx];
        int li = (int)(r.x >> 19);
        if (maskT[li] == 0.f) continue;          // out[dst] = 0 regardless
        int si = (int)(r.x & 0x7FFFFu);
        __half2 hc = *(__half2*)&r.y;
        float2 cf = __half22float2(hc);
        float2 pv = pp[si];
        float sE = fmaf(pv.x * inv0, cf.x, pv.y * inv1 * cf.y);
        atomicMax(&mxA[li], fmap_ord(sE));
    }
    __syncthreads();
    float wf0 = Wf[0], wf1 = Wf[1], bb = bf[0];
    for (int j = threadIdx.x; j < BSZ; j += CTH) {
        int i = base + j;
        if (i >= NNODES) continue;
        u32 m = mxA[j];   // 0 <=> no relevant edge; masked nodes output 0 anyway
        float h0, h1;
        if (m != 0u) { float v = funmap_ord(m); h0 = v; h1 = 1.f - v; }
        else { float2 pv = pp[i]; h0 = pv.x * inv0; h1 = pv.y * inv1; }
        out[i] = fmaf(wf0, h0, fmaf(wf1, h1, bb)) * maskT[j];
    }
}

// ---------------- fallback (round-2 proven, device-scope atomics) ----------------

__global__ __launch_bounds__(256) void k_init_f(float* s, float* msg, u32* mxb, float* accum) {
    int i = blockIdx.x * blockDim.x + threadIdx.x;
    if (i < NNODES) { s[i] = 0.f; mxb[i] = 0u; }
    if (i < 2 * NNODES) msg[i] = 0.f;
    if (i < 16) accum[i] = 0.f;
}

__global__ __launch_bounds__(256) void k_edge_attn_f(
    const int* __restrict__ ei, const float* __restrict__ ea,
    const float* __restrict__ We,
    const float2* __restrict__ q, const float4* __restrict__ kv,
    float* __restrict__ s, float* __restrict__ msg) {
    int e = blockIdx.x * blockDim.x + threadIdx.x;
    if (e >= NEDGES) return;
    float we00 = We[0], we01 = We[1], we10 = We[2], we11 = We[3];
    int si = ((const int2*)ei)[e].y;
    int di = ((const int2*)(ei + 2 * NEDGES))[e].y;
    float2 eav = ((const float2*)ea)[2 * e + 1];
    float4 kvv = kv[si];
    float2 qv = q[di];
    float e0 = fmaf(we00, eav.x, we01 * eav.y);
    float e1 = fmaf(we10, eav.x, we11 * eav.y);
    float alpha = fmaf(qv.x, kvv.x + e0, qv.y * (kvv.y + e1)) * 0.70710678118654752f;
    float a = __expf(alpha);
    unsafeAtomicAdd(&s[di], a);
    unsafeAtomicAdd(&msg[2 * di], a * (kvv.z + e0));
    unsafeAtomicAdd(&msg[2 * di + 1], a * (kvv.w + e1));
}

__global__ __launch_bounds__(256) void k_node_h_f(
    const float* __restrict__ x,
    const float* __restrict__ Wskip, const float* __restrict__ bskip,
    const float* __restrict__ s, float* __restrict__ msg, float* __restrict__ accum) {
    int i = blockIdx.x * blockDim.x + threadIdx.x;
    float h0 = 0.f, h1 = 0.f;
    if (i < NNODES) {
        float2 xv = ((const float2*)x)[i];
        float sk0 = fmaf(Wskip[0], xv.x, fmaf(Wskip[1], xv.y, bskip[0]));
        float sk1 = fmaf(Wskip[2], xv.x, fmaf(Wskip[3], xv.y, bskip[1]));
        float sv = s[i];
        float inv = sv > 0.f ? 1.f / sv : 0.f;
        h0 = fmaf(msg[2 * i], inv, sk0);
        h1 = fmaf(msg[2 * i + 1], inv, sk1);
        msg[2 * i] = h0;
        msg[2 * i + 1] = h1;
    }
    block_reduce_atomic4(h0, h1, h0 * h0, h1 * h1, accum);
}

__global__ __launch_bounds__(256) void k_edge_nmax_f(
    const int* __restrict__ ei, const float* __restrict__ ea,
    const float2* __restrict__ pp, const float* __restrict__ accum,
    u32* __restrict__ mxb) {
    int e = blockIdx.x * blockDim.x + threadIdx.x;
    if (e >= NEDGES) return;
    float inv0 = accum[12], inv1 = accum[13];
    int si = ((const int2*)ei)[e].y;
    int di = ((const int2*)(ei + 2 * NEDGES))[e].y;
    float2 c = ((const float2*)ea)[2 * e];
    float2 pv = pp[si];
    float sE = fmaf(pv.x * inv0, c.x, pv.y * inv1 * c.y);
    atomicMax(&mxb[di], fmap_ord(sE));
}

__global__ __launch_bounds__(256) void k_final_f(
    const u32* __restrict__ mxb, const float2* __restrict__ pp,
    const float* __restrict__ accum,
    const float* __restrict__ Wf, const float* __restrict__ bf,
    const float* __restrict__ mask, float* __restrict__ out) {
    int i = blockIdx.x * blockDim.x + threadIdx.x;
    if (i >= NNODES) return;
    u32 m = mxb[i];
    float h0, h1;
    if (m != 0u) {
        float v = funmap_ord(m);
        h0 = v;
        h1 = 1.f - v;
    } else {
        float2 pv = pp[i];
        h0 = pv.x * accum[12];
        h1 = pv.y * accum[13];
    }
    out[i] = fmaf(Wf[0], h0, fmaf(Wf[1], h1, bf[0])) * mask[i];
}

// ---------------- launch ----------------

extern "C" void kernel_launch(void* const* d_in, const int* in_sizes, int n_in,
                              void* d_out, int out_size, void* d_ws, size_t ws_size,
                              hipStream_t stream) {
    const float* x     = (const float*)d_in[0];
    const int*   ei    = (const int*)d_in[1];
    const float* ea    = (const float*)d_in[2];
    const float* mask  = (const float*)d_in[3];
    const float* Wq    = (const float*)d_in[4];
    const float* bq    = (const float*)d_in[5];
    const float* Wk    = (const float*)d_in[6];
    const float* bk    = (const float*)d_in[7];
    const float* Wv    = (const float*)d_in[8];
    const float* bv    = (const float*)d_in[9];
    const float* We    = (const float*)d_in[10];
    const float* Wskip = (const float*)d_in[11];
    const float* bskip = (const float*)d_in[12];
    const float* gamma = (const float*)d_in[13];
    const float* beta  = (const float*)d_in[14];
    const float* Wf    = (const float*)d_in[15];
    const float* bf    = (const float*)d_in[16];
    float* out = (float*)d_out;

    const size_t N = NNODES;
    const size_t E = NEDGES;
    const int B = 256;
    const int gridN = (NNODES + B - 1) / B;

    const int2*   src2 = (const int2*)ei;
    const int2*   dst2 = (const int2*)(ei + 2 * NEDGES);
    const float4* ea4  = (const float4*)ea;

    size_t need = 16 * N            // kv float4
                + 16 * E            // R1 float4
                + 8 * E             // R2 uint2
                + 8 * N             // q
                + 8 * N             // h
                + 8 * N             // p
                + 4 * (size_t)NBLK * BDIM
                + 4 * BDIM
                + 4 * (BDIM + 16)
                + 64;

    if (ws_size >= need) {
        char* base = (char*)d_ws;
        float4* kv = (float4*)base;                 base += 16 * N;
        float4* R1 = (float4*)base;                 base += 16 * E;
        uint2*  R2 = (uint2*)base;                  base += 8 * E;
        float2* q  = (float2*)base;                 base += 8 * N;
        float2* h  = (float2*)base;                 base += 8 * N;
        float2* p  = (float2*)base;                 base += 8 * N;
        u32*    M  = (u32*)base;                    base += 4 * (size_t)NBLK * BDIM;
        u32*    bT = (u32*)base;                    base += 4 * BDIM;
        u32*    bB = (u32*)base;                    base += 4 * (BDIM + 16);
        float*  accum = (float*)base;

        k_zero_accum<<<1, 64, 0, stream>>>(accum);
        k_node_prep<<<gridN, B, 0, stream>>>(x, Wq, bq, Wk, bk, Wv, bv, q, kv);
        k_hist<<<NBLK, B, 0, stream>>>(dst2, M);
        k_bucket_prefix<<<BDIM, B, 0, stream>>>(M, bT);
        k_scan_serial<<<1, B, 0, stream>>>(bT, bB);
        k_scatter_fused<<<NBLK, B, 0, stream>>>(src2, dst2, ea4, We, q, kv, M, bB, R1, R2);
        k_attn16<<<NBKT, CTH, 0, stream>>>(R1, bB, bT, x, Wskip, bskip, h, accum);
        k_ln_final<<<1, 1, 0, stream>>>(gamma, beta, accum);
        k_softmax<<<gridN, B, 0, stream>>>(h, p, accum);
        k_sm_final<<<1, 1, 0, stream>>>(accum);
        k_nmax16<<<NBKT, CTH, 0, stream>>>(R2, bB, bT, p, accum, Wf, bf, mask, out);
    } else {
        float*  q   = (float*)d_ws;
        float*  kvf = q + 2 * N;
        float*  s   = kvf + 4 * N;
        float*  msg = s + N;
        u32*    mxb = (u32*)(msg + 2 * N);
        float*  accum = (float*)(mxb + N);
        int grid2N = (int)((2 * N + B - 1) / B);
        int gridE  = (NEDGES + B - 1) / B;

        k_init_f<<<grid2N, B, 0, stream>>>(s, msg, mxb, accum);
        k_node_prep<<<gridN, B, 0, stream>>>(x, Wq, bq, Wk, bk, Wv, bv, (float2*)q, (float4*)kvf);
        k_edge_attn_f<<<gridE, B, 0, stream>>>(ei, ea, We, (const float2*)q, (const float4*)kvf, s, msg);
        k_node_h_f<<<gridN, B, 0, stream>>>(x, Wskip, bskip, s, msg, accum);
        k_ln_final<<<1, 1, 0, stream>>>(gamma, beta, accum);
        k_softmax<<<gridN, B, 0, stream>>>((const float2*)msg, (float2*)q, accum);
        k_sm_final<<<1, 1, 0, stream>>>(accum);
        k_edge_nmax_f<<<gridE, B, 0, stream>>>(ei, ea, (const float2*)q, accum, mxb);
        k_final_f<<<gridN, B, 0, stream>>>(mxb, (const float2*)q, accum, Wf, bf, mask, out);
    }
}

// Round 14
// 669.368 us; speedup vs baseline: 1.5170x; 1.5170x over previous
//
#include <hip/hip_runtime.h>
#include <hip/hip_fp16.h>

#define NNODES 500000
#define NEDGES 16000000
#define NBLK 1024           // histogram/scatter blocks
#define EPB (NEDGES / NBLK) // 15625 edges per block (exact)
#define BSH 11              // bucket shift: 2048 nodes per bucket
#define BSZ 2048
#define NBKT 245            // ceil(NNODES / 2048)
#define BDIM 256            // padded bucket dimension (245 <= 256)
#define CHUNK 2048          // staged-scatter chunk (8 chunks per block)
#define KPC (CHUNK / 256)   // records per thread per chunk = 8
#define CTH 1024            // consumer threads per block

typedef unsigned long long u64;
typedef unsigned int u32;
typedef unsigned short u16;

// ---------------- helpers ----------------

__device__ __forceinline__ u32 fmap_ord(float x) {
    u32 u = __float_as_uint(x);
    return (u & 0x80000000u) ? ~u : (u | 0x80000000u);
}
__device__ __forceinline__ float funmap_ord(u32 u) {
    u32 bits = (u & 0x80000000u) ? (u ^ 0x80000000u) : ~u;
    return __uint_as_float(bits);
}

// block reduce for 256-thread blocks
__device__ __forceinline__ void block_reduce_atomic4(float v0, float v1, float v2, float v3,
                                                     float* dst) {
    for (int off = 32; off > 0; off >>= 1) {
        v0 += __shfl_down(v0, off, 64);
        v1 += __shfl_down(v1, off, 64);
        v2 += __shfl_down(v2, off, 64);
        v3 += __shfl_down(v3, off, 64);
    }
    __shared__ float red[4][4];
    int lane = threadIdx.x & 63, wid = threadIdx.x >> 6;
    if (lane == 0) { red[wid][0] = v0; red[wid][1] = v1; red[wid][2] = v2; red[wid][3] = v3; }
    __syncthreads();
    if (threadIdx.x < 4) {
        float t = red[0][threadIdx.x] + red[1][threadIdx.x] + red[2][threadIdx.x] + red[3][threadIdx.x];
        unsafeAtomicAdd(&dst[threadIdx.x], t);
    }
}

// block reduce for 1024-thread blocks (16 waves)
__device__ __forceinline__ void block_reduce_atomic4_w16(float v0, float v1, float v2, float v3,
                                                         float* dst) {
    for (int off = 32; off > 0; off >>= 1) {
        v0 += __shfl_down(v0, off, 64);
        v1 += __shfl_down(v1, off, 64);
        v2 += __shfl_down(v2, off, 64);
        v3 += __shfl_down(v3, off, 64);
    }
    __shared__ float red[16][4];
    int lane = threadIdx.x & 63, wid = threadIdx.x >> 6;
    if (lane == 0) { red[wid][0] = v0; red[wid][1] = v1; red[wid][2] = v2; red[wid][3] = v3; }
    __syncthreads();
    if (threadIdx.x < 4) {
        float t = 0.f;
        #pragma unroll
        for (int w = 0; w < 16; ++w) t += red[w][threadIdx.x];
        unsafeAtomicAdd(&dst[threadIdx.x], t);
    }
}

// ---------------- shared kernels ----------------

__global__ __launch_bounds__(64) void k_zero_accum(float* accum) {
    if (threadIdx.x < 16) accum[threadIdx.x] = 0.f;
}

// per-node linears: q, k, v
__global__ __launch_bounds__(256) void k_node_prep(
    const float* __restrict__ x,
    const float* __restrict__ Wq, const float* __restrict__ bq,
    const float* __restrict__ Wk, const float* __restrict__ bk,
    const float* __restrict__ Wv, const float* __restrict__ bv,
    float2* __restrict__ q, float4* __restrict__ kv) {
    int i = blockIdx.x * blockDim.x + threadIdx.x;
    if (i >= NNODES) return;
    float2 xv = ((const float2*)x)[i];
    float q0 = fmaf(Wq[0], xv.x, fmaf(Wq[1], xv.y, bq[0]));
    float q1 = fmaf(Wq[2], xv.x, fmaf(Wq[3], xv.y, bq[1]));
    float k0 = fmaf(Wk[0], xv.x, fmaf(Wk[1], xv.y, bk[0]));
    float k1 = fmaf(Wk[2], xv.x, fmaf(Wk[3], xv.y, bk[1]));
    float v0 = fmaf(Wv[0], xv.x, fmaf(Wv[1], xv.y, bv[0]));
    float v1 = fmaf(Wv[2], xv.x, fmaf(Wv[3], xv.y, bv[1]));
    q[i] = make_float2(q0, q1);
    kv[i] = make_float4(k0, k1, v0, v1);
}

// 1-thread: layernorm scale/shift
__global__ void k_ln_final(const float* __restrict__ gamma, const float* __restrict__ beta,
                           float* __restrict__ accum) {
    float n = (float)NNODES;
    float mu0 = accum[0] / n, mu1 = accum[1] / n;
    float var0 = accum[2] / n - mu0 * mu0;
    float var1 = accum[3] / n - mu1 * mu1;
    float sc0 = gamma[0] * rsqrtf(var0 + 1e-5f);
    float sc1 = gamma[1] * rsqrtf(var1 + 1e-5f);
    accum[8] = sc0;
    accum[9] = sc1;
    accum[10] = beta[0] - mu0 * sc0;
    accum[11] = beta[1] - mu1 * sc1;
}

// per-node: normalized h -> exp (f32 p-plane); reduce column sums
__global__ __launch_bounds__(256) void k_softmax(
    const float2* __restrict__ h, float2* __restrict__ pp, float* __restrict__ accum) {
    int i = blockIdx.x * blockDim.x + threadIdx.x;
    float p0 = 0.f, p1 = 0.f;
    if (i < NNODES) {
        float sc0 = accum[8], sc1 = accum[9], sh0 = accum[10], sh1 = accum[11];
        float2 hv = h[i];
        p0 = __expf(fmaf(hv.x, sc0, sh0));
        p1 = __expf(fmaf(hv.y, sc1, sh1));
        pp[i] = make_float2(p0, p1);
    }
    block_reduce_atomic4(p0, p1, 0.f, 0.f, accum + 4);
}

// 1-thread: softmax denominators -> reciprocals
__global__ void k_sm_final(float* __restrict__ accum) {
    accum[12] = 1.f / accum[4];
    accum[13] = 1.f / accum[5];
}

// ---------------- sort infrastructure ----------------

// per-block LDS histogram of dst buckets -> counts matrix M[blk][bucket]
__global__ __launch_bounds__(256) void k_hist(const int2* __restrict__ dst2, u32* __restrict__ M) {
    __shared__ u32 hist[BDIM];
    if (threadIdx.x < BDIM) hist[threadIdx.x] = 0u;
    __syncthreads();
    int beg = blockIdx.x * EPB, end = beg + EPB;
    #pragma unroll 4
    for (int e = beg + threadIdx.x; e < end; e += 256)
        atomicAdd(&hist[dst2[e].y >> BSH], 1u);
    __syncthreads();
    u32* row = M + (size_t)blockIdx.x * BDIM;
    if (threadIdx.x < BDIM) row[threadIdx.x] = hist[threadIdx.x];
}

// per bucket: column prefix over blocks (in place), bucket totals out
__global__ __launch_bounds__(256) void k_bucket_prefix(u32* __restrict__ M, u32* __restrict__ bucketTotal) {
    __shared__ u32 col[NBLK];
    int b = blockIdx.x;
    for (int j = threadIdx.x; j < NBLK; j += 256) col[j] = M[(size_t)j * BDIM + b];
    __syncthreads();
    if (threadIdx.x == 0) {
        u32 run = 0;
        for (int j = 0; j < NBLK; ++j) { u32 c = col[j]; col[j] = run; run += c; }
        bucketTotal[b] = run;
    }
    __syncthreads();
    for (int j = threadIdx.x; j < NBLK; j += 256) M[(size_t)j * BDIM + b] = col[j];
}

// exclusive scan of bucket totals (serial in LDS)
__global__ __launch_bounds__(256) void k_scan_serial(const u32* __restrict__ bucketTotal,
                                                     u32* __restrict__ bucketBase) {
    __shared__ u32 t[BDIM];
    __shared__ u32 o[BDIM + 1];
    if (threadIdx.x < BDIM) t[threadIdx.x] = bucketTotal[threadIdx.x];
    __syncthreads();
    if (threadIdx.x == 0) {
        u32 run = 0;
        for (int j = 0; j < BDIM; ++j) { o[j] = run; run += t[j]; }
        o[BDIM] = run;
    }
    __syncthreads();
    for (int j = threadIdx.x; j < BDIM + 1; j += 256) bucketBase[j] = o[j];
}

// ---------------- LDS-staged coalesced scatter (16B records, round-12 proven) ----------------
// record = float4: [idx | e0 f32 | e1 f32 | pk_f16(c0,c1)], idx = si | (di&2047)<<19

__global__ __launch_bounds__(256) void k_scatter_stg(
    const int2* __restrict__ src2, const int2* __restrict__ dst2,
    const float4* __restrict__ ea4, const float* __restrict__ We,
    const u32* __restrict__ M, const u32* __restrict__ bucketBase,
    float4* __restrict__ R) {
    __shared__ u32 hist[BDIM];
    __shared__ u32 lbase[BDIM];
    __shared__ u32 gcur[BDIM];
    __shared__ u32 wsum[4];
    __shared__ float4 buf[CHUNK];
    __shared__ u16 bkt[CHUNK];

    const u32* row = M + (size_t)blockIdx.x * BDIM;
    if (threadIdx.x < BDIM) gcur[threadIdx.x] = row[threadIdx.x] + bucketBase[threadIdx.x];
    float we00 = We[0], we01 = We[1], we10 = We[2], we11 = We[3];
    int beg = blockIdx.x * EPB;
    int lane = threadIdx.x & 63, wid = threadIdx.x >> 6;

    for (int c0 = 0; c0 < EPB; c0 += CHUNK) {
        int cn = min(CHUNK, EPB - c0);
        if (threadIdx.x < BDIM) hist[threadIdx.x] = 0u;
        __syncthreads();

        // load chunk, build records in regs, count + rank via LDS atomics
        float4 recs[KPC]; u32 bks[KPC]; u32 rnk[KPC]; bool val[KPC];
        #pragma unroll
        for (int k = 0; k < KPC; ++k) {
            int tt = k * 256 + threadIdx.x;
            val[k] = tt < cn;
            if (val[k]) {
                int e = beg + c0 + tt;
                int si = src2[e].y;                 // edge_index[0, 2e+1]
                int di = dst2[e].y;                 // edge_index[1, 2e+1]
                float4 eav = ea4[e];                // rows 2e (clause), 2e+1 (attn)
                float e0 = fmaf(we00, eav.z, we01 * eav.w);
                float e1 = fmaf(we10, eav.z, we11 * eav.w);
                __half2 hc = __floats2half2_rn(eav.x, eav.y);
                u32 b = (u32)di >> BSH;
                u32 idx = (u32)si | ((u32)(di & (BSZ - 1)) << 19);
                recs[k] = make_float4(__uint_as_float(idx), e0, e1,
                                      __uint_as_float(*(u32*)&hc));
                bks[k] = b;
                rnk[k] = atomicAdd(&hist[b], 1u);
            }
        }
        __syncthreads();

        // exclusive scan of hist[0..BDIM): one entry per thread
        u32 s = hist[threadIdx.x];
        u32 inc = s;
        #pragma unroll
        for (int d = 1; d < 64; d <<= 1) {
            u32 v = __shfl_up(inc, d, 64);
            if (lane >= d) inc += v;
        }
        if (lane == 63) wsum[wid] = inc;
        __syncthreads();
        u32 woff = 0;
        for (int w = 0; w < wid; ++w) woff += wsum[w];
        lbase[threadIdx.x] = woff + inc - s;
        __syncthreads();

        // bucket-sorted scatter into LDS
        #pragma unroll
        for (int k = 0; k < KPC; ++k) {
            if (val[k]) {
                u32 p = lbase[bks[k]] + rnk[k];
                buf[p] = recs[k];
                bkt[p] = (u16)bks[k];
            }
        }
        __syncthreads();

        // coalesced flush: consecutive j -> consecutive global addresses per run
        for (int j = threadIdx.x; j < cn; j += 256) {
            u32 b = bkt[j];
            R[(size_t)gcur[b] + (u32)j - lbase[b]] = buf[j];
        }
        __syncthreads();

        // advance global cursors
        if (threadIdx.x < BDIM) gcur[threadIdx.x] += hist[threadIdx.x];
        __syncthreads();
    }
}

// edge pass 1: per-bucket LDS accumulate, 4x-unrolled loads for gather MLP
__global__ __launch_bounds__(CTH) void k_attn16(
    const float4* __restrict__ R,
    const u32* __restrict__ bucketBase, const u32* __restrict__ bucketTotal,
    const float4* __restrict__ kv, const float2* __restrict__ qp,
    const float* __restrict__ x,
    const float* __restrict__ Wskip, const float* __restrict__ bskip,
    float2* __restrict__ h, float* __restrict__ accum) {
    __shared__ float sA[BSZ], m0A[BSZ], m1A[BSZ];
    __shared__ float2 qT[BSZ];
    int b = blockIdx.x, base = b << BSH;
    for (int j = threadIdx.x; j < BSZ; j += CTH) {
        sA[j] = 0.f; m0A[j] = 0.f; m1A[j] = 0.f;
        int i = base + j;
        qT[j] = (i < NNODES) ? qp[i] : make_float2(0.f, 0.f);
    }
    __syncthreads();
    int beg = bucketBase[b], end = beg + bucketTotal[b];
    int idx = beg + threadIdx.x;
    // 4x unrolled main loop: 4 independent record loads, then 4 independent gathers
    for (; idx + 3 * CTH < end; idx += 4 * CTH) {
        float4 r[4];
        #pragma unroll
        for (int u = 0; u < 4; ++u) r[u] = R[idx + u * CTH];
        int si[4], li[4];
        float4 kvv[4];
        #pragma unroll
        for (int u = 0; u < 4; ++u) {
            u32 rec = __float_as_uint(r[u].x);
            si[u] = rec & 0x7FFFFu;
            li[u] = rec >> 19;
            kvv[u] = kv[si[u]];
        }
        #pragma unroll
        for (int u = 0; u < 4; ++u) {
            float2 qv = qT[li[u]];
            float alpha = fmaf(qv.x, kvv[u].x + r[u].y, qv.y * (kvv[u].y + r[u].z)) * 0.70710678118654752f;
            float a = __expf(alpha);
            atomicAdd(&sA[li[u]], a);
            atomicAdd(&m0A[li[u]], a * (kvv[u].z + r[u].y));
            atomicAdd(&m1A[li[u]], a * (kvv[u].w + r[u].z));
        }
    }
    for (; idx < end; idx += CTH) {
        float4 r = R[idx];
        u32 rec = __float_as_uint(r.x);
        int si = rec & 0x7FFFFu;
        int li = rec >> 19;
        float4 kvv = kv[si];
        float2 qv = qT[li];
        float alpha = fmaf(qv.x, kvv.x + r.y, qv.y * (kvv.y + r.z)) * 0.70710678118654752f;
        float a = __expf(alpha);
        atomicAdd(&sA[li], a);
        atomicAdd(&m0A[li], a * (kvv.z + r.y));
        atomicAdd(&m1A[li], a * (kvv.w + r.z));
    }
    __syncthreads();
    float r0 = 0.f, r1 = 0.f, r2 = 0.f, r3 = 0.f;
    float w00 = Wskip[0], w01 = Wskip[1], w10 = Wskip[2], w11 = Wskip[3];
    float c0 = bskip[0], c1 = bskip[1];
    for (int j = threadIdx.x; j < BSZ; j += CTH) {
        int i = base + j;
        if (i < NNODES) {
            float2 xv = ((const float2*)x)[i];
            float s = sA[j];
            float inv = s > 0.f ? 1.f / s : 0.f;
            float h0 = fmaf(m0A[j], inv, fmaf(w00, xv.x, fmaf(w01, xv.y, c0)));
            float h1 = fmaf(m1A[j], inv, fmaf(w10, xv.x, fmaf(w11, xv.y, c1)));
            h[i] = make_float2(h0, h1);
            r0 += h0; r1 += h1; r2 += h0 * h0; r3 += h1 * h1;
        }
    }
    block_reduce_atomic4_w16(r0, r1, r2, r3, accum);
}

// edge pass 2: per-bucket LDS max (skip masked dst), 4x-unrolled, fused final output
__global__ __launch_bounds__(CTH) void k_nmax16(
    const float4* __restrict__ R,
    const u32* __restrict__ bucketBase, const u32* __restrict__ bucketTotal,
    const float2* __restrict__ pp, const float* __restrict__ accum,
    const float* __restrict__ Wf, const float* __restrict__ bf,
    const float* __restrict__ mask, float* __restrict__ out) {
    __shared__ u32 mxA[BSZ];
    __shared__ float maskT[BSZ];
    int b = blockIdx.x, base = b << BSH;
    for (int j = threadIdx.x; j < BSZ; j += CTH) {
        mxA[j] = 0u;
        int i = base + j;
        maskT[j] = (i < NNODES) ? mask[i] : 0.f;
    }
    __syncthreads();
    float inv0 = accum[12], inv1 = accum[13];
    int beg = bucketBase[b], end = beg + bucketTotal[b];
    int idx = beg + threadIdx.x;
    for (; idx + 3 * CTH < end; idx += 4 * CTH) {
        float4 r[4];
        #pragma unroll
        for (int u = 0; u < 4; ++u) r[u] = R[idx + u * CTH];
        #pragma unroll
        for (int u = 0; u < 4; ++u) {
            u32 rec = __float_as_uint(r[u].x);
            int li = rec >> 19;
            if (maskT[li] == 0.f) continue;
            int si = rec & 0x7FFFFu;
            u32 hcbits = __float_as_uint(r[u].w);
            __half2 hc = *(__half2*)&hcbits;
            float2 cf = __half22float2(hc);
            float2 pv = pp[si];
            float sE = fmaf(pv.x * inv0, cf.x, pv.y * inv1 * cf.y);
            atomicMax(&mxA[li], fmap_ord(sE));
        }
    }
    for (; idx < end; idx += CTH) {
        float4 r = R[idx];
        u32 rec = __float_as_uint(r.x);
        int li = rec >> 19;
        if (maskT[li] == 0.f) continue;
        int si = rec & 0x7FFFFu;
        u32 hcbits = __float_as_uint(r.w);
        __half2 hc = *(__half2*)&hcbits;
        float2 cf = __half22float2(hc);
        float2 pv = pp[si];
        float sE = fmaf(pv.x * inv0, cf.x, pv.y * inv1 * cf.y);
        atomicMax(&mxA[li], fmap_ord(sE));
    }
    __syncthreads();
    float wf0 = Wf[0], wf1 = Wf[1], bb = bf[0];
    for (int j = threadIdx.x; j < BSZ; j += CTH) {
        int i = base + j;
        if (i >= NNODES) continue;
        u32 m = mxA[j];   // 0 <=> no relevant edge; masked nodes output 0 anyway
        float h0, h1;
        if (m != 0u) { float v = funmap_ord(m); h0 = v; h1 = 1.f - v; }
        else { float2 pv = pp[i]; h0 = pv.x * inv0; h1 = pv.y * inv1; }
        out[i] = fmaf(wf0, h0, fmaf(wf1, h1, bb)) * maskT[j];
    }
}

// ---------------- fallback (round-2 proven, device-scope atomics) ----------------

__global__ __launch_bounds__(256) void k_init_f(float* s, float* msg, u32* mxb, float* accum) {
    int i = blockIdx.x * blockDim.x + threadIdx.x;
    if (i < NNODES) { s[i] = 0.f; mxb[i] = 0u; }
    if (i < 2 * NNODES) msg[i] = 0.f;
    if (i < 16) accum[i] = 0.f;
}

__global__ __launch_bounds__(256) void k_edge_attn_f(
    const int* __restrict__ ei, const float* __restrict__ ea,
    const float* __restrict__ We,
    const float2* __restrict__ q, const float4* __restrict__ kv,
    float* __restrict__ s, float* __restrict__ msg) {
    int e = blockIdx.x * blockDim.x + threadIdx.x;
    if (e >= NEDGES) return;
    float we00 = We[0], we01 = We[1], we10 = We[2], we11 = We[3];
    int si = ((const int2*)ei)[e].y;
    int di = ((const int2*)(ei + 2 * NEDGES))[e].y;
    float2 eav = ((const float2*)ea)[2 * e + 1];
    float4 kvv = kv[si];
    float2 qv = q[di];
    float e0 = fmaf(we00, eav.x, we01 * eav.y);
    float e1 = fmaf(we10, eav.x, we11 * eav.y);
    float alpha = fmaf(qv.x, kvv.x + e0, qv.y * (kvv.y + e1)) * 0.70710678118654752f;
    float a = __expf(alpha);
    unsafeAtomicAdd(&s[di], a);
    unsafeAtomicAdd(&msg[2 * di], a * (kvv.z + e0));
    unsafeAtomicAdd(&msg[2 * di + 1], a * (kvv.w + e1));
}

__global__ __launch_bounds__(256) void k_node_h_f(
    const float* __restrict__ x,
    const float* __restrict__ Wskip, const float* __restrict__ bskip,
    const float* __restrict__ s, float* __restrict__ msg, float* __restrict__ accum) {
    int i = blockIdx.x * blockDim.x + threadIdx.x;
    float h0 = 0.f, h1 = 0.f;
    if (i < NNODES) {
        float2 xv = ((const float2*)x)[i];
        float sk0 = fmaf(Wskip[0], xv.x, fmaf(Wskip[1], xv.y, bskip[0]));
        float sk1 = fmaf(Wskip[2], xv.x, fmaf(Wskip[3], xv.y, bskip[1]));
        float sv = s[i];
        float inv = sv > 0.f ? 1.f / sv : 0.f;
        h0 = fmaf(msg[2 * i], inv, sk0);
        h1 = fmaf(msg[2 * i + 1], inv, sk1);
        msg[2 * i] = h0;
        msg[2 * i + 1] = h1;
    }
    block_reduce_atomic4(h0, h1, h0 * h0, h1 * h1, accum);
}

__global__ __launch_bounds__(256) void k_edge_nmax_f(
    const int* __restrict__ ei, const float* __restrict__ ea,
    const float2* __restrict__ pp, const float* __restrict__ accum,
    u32* __restrict__ mxb) {
    int e = blockIdx.x * blockDim.x + threadIdx.x;
    if (e >= NEDGES) return;
    float inv0 = accum[12], inv1 = accum[13];
    int si = ((const int2*)ei)[e].y;
    int di = ((const int2*)(ei + 2 * NEDGES))[e].y;
    float2 c = ((const float2*)ea)[2 * e];
    float2 pv = pp[si];
    float sE = fmaf(pv.x * inv0, c.x, pv.y * inv1 * c.y);
    atomicMax(&mxb[di], fmap_ord(sE));
}

__global__ __launch_bounds__(256) void k_final_f(
    const u32* __restrict__ mxb, const float2* __restrict__ pp,
    const float* __restrict__ accum,
    const float* __restrict__ Wf, const float* __restrict__ bf,
    const float* __restrict__ mask, float* __restrict__ out) {
    int i = blockIdx.x * blockDim.x + threadIdx.x;
    if (i >= NNODES) return;
    u32 m = mxb[i];
    float h0, h1;
    if (m != 0u) {
        float v = funmap_ord(m);
        h0 = v;
        h1 = 1.f - v;
    } else {
        float2 pv = pp[i];
        h0 = pv.x * accum[12];
        h1 = pv.y * accum[13];
    }
    out[i] = fmaf(Wf[0], h0, fmaf(Wf[1], h1, bf[0])) * mask[i];
}

// ---------------- launch ----------------

extern "C" void kernel_launch(void* const* d_in, const int* in_sizes, int n_in,
                              void* d_out, int out_size, void* d_ws, size_t ws_size,
                              hipStream_t stream) {
    const float* x     = (const float*)d_in[0];
    const int*   ei    = (const int*)d_in[1];
    const float* ea    = (const float*)d_in[2];
    const float* mask  = (const float*)d_in[3];
    const float* Wq    = (const float*)d_in[4];
    const float* bq    = (const float*)d_in[5];
    const float* Wk    = (const float*)d_in[6];
    const float* bk    = (const float*)d_in[7];
    const float* Wv    = (const float*)d_in[8];
    const float* bv    = (const float*)d_in[9];
    const float* We    = (const float*)d_in[10];
    const float* Wskip = (const float*)d_in[11];
    const float* bskip = (const float*)d_in[12];
    const float* gamma = (const float*)d_in[13];
    const float* beta  = (const float*)d_in[14];
    const float* Wf    = (const float*)d_in[15];
    const float* bf    = (const float*)d_in[16];
    float* out = (float*)d_out;

    const size_t N = NNODES;
    const size_t E = NEDGES;
    const int B = 256;
    const int gridN = (NNODES + B - 1) / B;

    const int2*   src2 = (const int2*)ei;
    const int2*   dst2 = (const int2*)(ei + 2 * NEDGES);
    const float4* ea4  = (const float4*)ea;

    size_t need16 = 16 * N            // kv float4
                  + 16 * E            // R records (1 x float4)
                  + 8 * N             // q
                  + 8 * N             // h
                  + 8 * N             // p
                  + 4 * (size_t)NBLK * BDIM
                  + 4 * BDIM
                  + 4 * (BDIM + 16)
                  + 64;

    if (ws_size >= need16) {
        char* base = (char*)d_ws;
        float4* kv = (float4*)base;                 base += 16 * N;
        float4* R  = (float4*)base;                 base += 16 * E;
        float2* q  = (float2*)base;                 base += 8 * N;
        float2* h  = (float2*)base;                 base += 8 * N;
        float2* p  = (float2*)base;                 base += 8 * N;
        u32*    M  = (u32*)base;                    base += 4 * (size_t)NBLK * BDIM;
        u32*    bT = (u32*)base;                    base += 4 * BDIM;
        u32*    bB = (u32*)base;                    base += 4 * (BDIM + 16);
        float*  accum = (float*)base;

        k_zero_accum<<<1, 64, 0, stream>>>(accum);
        k_node_prep<<<gridN, B, 0, stream>>>(x, Wq, bq, Wk, bk, Wv, bv, q, kv);
        k_hist<<<NBLK, B, 0, stream>>>(dst2, M);
        k_bucket_prefix<<<BDIM, B, 0, stream>>>(M, bT);
        k_scan_serial<<<1, B, 0, stream>>>(bT, bB);
        k_scatter_stg<<<NBLK, B, 0, stream>>>(src2, dst2, ea4, We, M, bB, R);
        k_attn16<<<NBKT, CTH, 0, stream>>>(R, bB, bT, kv, q, x, Wskip, bskip, h, accum);
        k_ln_final<<<1, 1, 0, stream>>>(gamma, beta, accum);
        k_softmax<<<gridN, B, 0, stream>>>(h, p, accum);
        k_sm_final<<<1, 1, 0, stream>>>(accum);
        k_nmax16<<<NBKT, CTH, 0, stream>>>(R, bB, bT, p, accum, Wf, bf, mask, out);
    } else {
        float*  q   = (float*)d_ws;
        float*  kvf = q + 2 * N;
        float*  s   = kvf + 4 * N;
        float*  msg = s + N;
        u32*    mxb = (u32*)(msg + 2 * N);
        float*  accum = (float*)(mxb + N);
        int grid2N = (int)((2 * N + B - 1) / B);
        int gridE  = (NEDGES + B - 1) / B;

        k_init_f<<<grid2N, B, 0, stream>>>(s, msg, mxb, accum);
        k_node_prep<<<gridN, B, 0, stream>>>(x, Wq, bq, Wk, bk, Wv, bv, (float2*)q, (float4*)kvf);
        k_edge_attn_f<<<gridE, B, 0, stream>>>(ei, ea, We, (const float2*)q, (const float4*)kvf, s, msg);
        k_node_h_f<<<gridN, B, 0, stream>>>(x, Wskip, bskip, s, msg, accum);
        k_ln_final<<<1, 1, 0, stream>>>(gamma, beta, accum);
        k_softmax<<<gridN, B, 0, stream>>>((const float2*)msg, (float2*)q, accum);
        k_sm_final<<<1, 1, 0, stream>>>(accum);
        k_edge_nmax_f<<<gridE, B, 0, stream>>>(ei, ea, (const float2*)q, accum, mxb);
        k_final_f<<<gridN, B, 0, stream>>>(mxb, (const float2*)q, accum, Wf, bf, mask, out);
    }
}

// Round 16
// 649.354 us; speedup vs baseline: 1.5637x; 1.0308x over previous
//
#include <hip/hip_runtime.h>
#include <hip/hip_fp16.h>

#define NNODES 500000
#define NEDGES 16000000
#define NBLK 1024           // histogram/scatter blocks
#define EPB (NEDGES / NBLK) // 15625 edges per block (exact)
#define BSH 11              // bucket shift: 2048 nodes per bucket
#define BSZ 2048
#define NBKT 245            // ceil(NNODES / 2048)
#define BDIM 256            // padded bucket dimension (245 <= 256)
#define CHUNK 2048          // staged-scatter chunk (8 chunks per block)
#define KPC (CHUNK / 256)   // records per thread per chunk = 8
#define CTH 1024            // consumer threads per block

typedef unsigned long long u64;
typedef unsigned int u32;
typedef unsigned short u16;
typedef float vf4 __attribute__((ext_vector_type(4)));

// ---------------- helpers ----------------

__device__ __forceinline__ u32 fmap_ord(float x) {
    u32 u = __float_as_uint(x);
    return (u & 0x80000000u) ? ~u : (u | 0x80000000u);
}
__device__ __forceinline__ float funmap_ord(u32 u) {
    u32 bits = (u & 0x80000000u) ? (u ^ 0x80000000u) : ~u;
    return __uint_as_float(bits);
}

// nontemporal 16B load (builtin needs a native vector pointer, not HIP_vector_type)
__device__ __forceinline__ float4 ntload4(const float4* p) {
    vf4 v = __builtin_nontemporal_load((const vf4*)p);
    return make_float4(v.x, v.y, v.z, v.w);
}

// block reduce for 256-thread blocks
__device__ __forceinline__ void block_reduce_atomic4(float v0, float v1, float v2, float v3,
                                                     float* dst) {
    for (int off = 32; off > 0; off >>= 1) {
        v0 += __shfl_down(v0, off, 64);
        v1 += __shfl_down(v1, off, 64);
        v2 += __shfl_down(v2, off, 64);
        v3 += __shfl_down(v3, off, 64);
    }
    __shared__ float red[4][4];
    int lane = threadIdx.x & 63, wid = threadIdx.x >> 6;
    if (lane == 0) { red[wid][0] = v0; red[wid][1] = v1; red[wid][2] = v2; red[wid][3] = v3; }
    __syncthreads();
    if (threadIdx.x < 4) {
        float t = red[0][threadIdx.x] + red[1][threadIdx.x] + red[2][threadIdx.x] + red[3][threadIdx.x];
        unsafeAtomicAdd(&dst[threadIdx.x], t);
    }
}

// block reduce for 1024-thread blocks (16 waves)
__device__ __forceinline__ void block_reduce_atomic4_w16(float v0, float v1, float v2, float v3,
                                                         float* dst) {
    for (int off = 32; off > 0; off >>= 1) {
        v0 += __shfl_down(v0, off, 64);
        v1 += __shfl_down(v1, off, 64);
        v2 += __shfl_down(v2, off, 64);
        v3 += __shfl_down(v3, off, 64);
    }
    __shared__ float red[16][4];
    int lane = threadIdx.x & 63, wid = threadIdx.x >> 6;
    if (lane == 0) { red[wid][0] = v0; red[wid][1] = v1; red[wid][2] = v2; red[wid][3] = v3; }
    __syncthreads();
    if (threadIdx.x < 4) {
        float t = 0.f;
        #pragma unroll
        for (int w = 0; w < 16; ++w) t += red[w][threadIdx.x];
        unsafeAtomicAdd(&dst[threadIdx.x], t);
    }
}

// ---------------- shared kernels ----------------

__global__ __launch_bounds__(64) void k_zero_accum(float* accum) {
    if (threadIdx.x < 16) accum[threadIdx.x] = 0.f;
}

// per-node linears: q (f32), kv packed fp16x4 (8B/node -> 4MB table, L2-resident)
__global__ __launch_bounds__(256) void k_node_prep(
    const float* __restrict__ x,
    const float* __restrict__ Wq, const float* __restrict__ bq,
    const float* __restrict__ Wk, const float* __restrict__ bk,
    const float* __restrict__ Wv, const float* __restrict__ bv,
    float2* __restrict__ q, uint2* __restrict__ kvh) {
    int i = blockIdx.x * blockDim.x + threadIdx.x;
    if (i >= NNODES) return;
    float2 xv = ((const float2*)x)[i];
    float q0 = fmaf(Wq[0], xv.x, fmaf(Wq[1], xv.y, bq[0]));
    float q1 = fmaf(Wq[2], xv.x, fmaf(Wq[3], xv.y, bq[1]));
    float k0 = fmaf(Wk[0], xv.x, fmaf(Wk[1], xv.y, bk[0]));
    float k1 = fmaf(Wk[2], xv.x, fmaf(Wk[3], xv.y, bk[1]));
    float v0 = fmaf(Wv[0], xv.x, fmaf(Wv[1], xv.y, bv[0]));
    float v1 = fmaf(Wv[2], xv.x, fmaf(Wv[3], xv.y, bv[1]));
    q[i] = make_float2(q0, q1);
    __half2 hk = __floats2half2_rn(k0, k1);
    __half2 hv = __floats2half2_rn(v0, v1);
    kvh[i] = make_uint2(*(u32*)&hk, *(u32*)&hv);
}

// 1-thread: layernorm scale/shift
__global__ void k_ln_final(const float* __restrict__ gamma, const float* __restrict__ beta,
                           float* __restrict__ accum) {
    float n = (float)NNODES;
    float mu0 = accum[0] / n, mu1 = accum[1] / n;
    float var0 = accum[2] / n - mu0 * mu0;
    float var1 = accum[3] / n - mu1 * mu1;
    float sc0 = gamma[0] * rsqrtf(var0 + 1e-5f);
    float sc1 = gamma[1] * rsqrtf(var1 + 1e-5f);
    accum[8] = sc0;
    accum[9] = sc1;
    accum[10] = beta[0] - mu0 * sc0;
    accum[11] = beta[1] - mu1 * sc1;
}

// per-node: normalized h -> exp (f32 p-plane); reduce column sums
__global__ __launch_bounds__(256) void k_softmax(
    const float2* __restrict__ h, float2* __restrict__ pp, float* __restrict__ accum) {
    int i = blockIdx.x * blockDim.x + threadIdx.x;
    float p0 = 0.f, p1 = 0.f;
    if (i < NNODES) {
        float sc0 = accum[8], sc1 = accum[9], sh0 = accum[10], sh1 = accum[11];
        float2 hv = h[i];
        p0 = __expf(fmaf(hv.x, sc0, sh0));
        p1 = __expf(fmaf(hv.y, sc1, sh1));
        pp[i] = make_float2(p0, p1);
    }
    block_reduce_atomic4(p0, p1, 0.f, 0.f, accum + 4);
}

// 1-thread: softmax denominators -> reciprocals
__global__ void k_sm_final(float* __restrict__ accum) {
    accum[12] = 1.f / accum[4];
    accum[13] = 1.f / accum[5];
}

// ---------------- sort infrastructure ----------------

// per-block LDS histogram of dst buckets -> counts matrix M[blk][bucket]
__global__ __launch_bounds__(256) void k_hist(const int2* __restrict__ dst2, u32* __restrict__ M) {
    __shared__ u32 hist[BDIM];
    if (threadIdx.x < BDIM) hist[threadIdx.x] = 0u;
    __syncthreads();
    int beg = blockIdx.x * EPB, end = beg + EPB;
    #pragma unroll 4
    for (int e = beg + threadIdx.x; e < end; e += 256)
        atomicAdd(&hist[dst2[e].y >> BSH], 1u);
    __syncthreads();
    u32* row = M + (size_t)blockIdx.x * BDIM;
    if (threadIdx.x < BDIM) row[threadIdx.x] = hist[threadIdx.x];
}

// per bucket: column prefix over blocks (in place), bucket totals out
__global__ __launch_bounds__(256) void k_bucket_prefix(u32* __restrict__ M, u32* __restrict__ bucketTotal) {
    __shared__ u32 col[NBLK];
    int b = blockIdx.x;
    for (int j = threadIdx.x; j < NBLK; j += 256) col[j] = M[(size_t)j * BDIM + b];
    __syncthreads();
    if (threadIdx.x == 0) {
        u32 run = 0;
        for (int j = 0; j < NBLK; ++j) { u32 c = col[j]; col[j] = run; run += c; }
        bucketTotal[b] = run;
    }
    __syncthreads();
    for (int j = threadIdx.x; j < NBLK; j += 256) M[(size_t)j * BDIM + b] = col[j];
}

// exclusive scan of bucket totals (serial in LDS)
__global__ __launch_bounds__(256) void k_scan_serial(const u32* __restrict__ bucketTotal,
                                                     u32* __restrict__ bucketBase) {
    __shared__ u32 t[BDIM];
    __shared__ u32 o[BDIM + 1];
    if (threadIdx.x < BDIM) t[threadIdx.x] = bucketTotal[threadIdx.x];
    __syncthreads();
    if (threadIdx.x == 0) {
        u32 run = 0;
        for (int j = 0; j < BDIM; ++j) { o[j] = run; run += t[j]; }
        o[BDIM] = run;
    }
    __syncthreads();
    for (int j = threadIdx.x; j < BDIM + 1; j += 256) bucketBase[j] = o[j];
}

// ---------------- LDS-staged coalesced scatter (16B records, round-12 proven) ----------------
// record = float4: [idx | e0 f32 | e1 f32 | pk_f16(c0,c1)], idx = si | (di&2047)<<19

__global__ __launch_bounds__(256) void k_scatter_stg(
    const int2* __restrict__ src2, const int2* __restrict__ dst2,
    const float4* __restrict__ ea4, const float* __restrict__ We,
    const u32* __restrict__ M, const u32* __restrict__ bucketBase,
    float4* __restrict__ R) {
    __shared__ u32 hist[BDIM];
    __shared__ u32 lbase[BDIM];
    __shared__ u32 gcur[BDIM];
    __shared__ u32 wsum[4];
    __shared__ float4 buf[CHUNK];
    __shared__ u16 bkt[CHUNK];

    const u32* row = M + (size_t)blockIdx.x * BDIM;
    if (threadIdx.x < BDIM) gcur[threadIdx.x] = row[threadIdx.x] + bucketBase[threadIdx.x];
    float we00 = We[0], we01 = We[1], we10 = We[2], we11 = We[3];
    int beg = blockIdx.x * EPB;
    int lane = threadIdx.x & 63, wid = threadIdx.x >> 6;

    for (int c0 = 0; c0 < EPB; c0 += CHUNK) {
        int cn = min(CHUNK, EPB - c0);
        if (threadIdx.x < BDIM) hist[threadIdx.x] = 0u;
        __syncthreads();

        // load chunk, build records in regs, count + rank via LDS atomics
        float4 recs[KPC]; u32 bks[KPC]; u32 rnk[KPC]; bool val[KPC];
        #pragma unroll
        for (int k = 0; k < KPC; ++k) {
            int tt = k * 256 + threadIdx.x;
            val[k] = tt < cn;
            if (val[k]) {
                int e = beg + c0 + tt;
                int si = src2[e].y;                 // edge_index[0, 2e+1]
                int di = dst2[e].y;                 // edge_index[1, 2e+1]
                float4 eav = ea4[e];                // rows 2e (clause), 2e+1 (attn)
                float e0 = fmaf(we00, eav.z, we01 * eav.w);
                float e1 = fmaf(we10, eav.z, we11 * eav.w);
                __half2 hc = __floats2half2_rn(eav.x, eav.y);
                u32 b = (u32)di >> BSH;
                u32 idx = (u32)si | ((u32)(di & (BSZ - 1)) << 19);
                recs[k] = make_float4(__uint_as_float(idx), e0, e1,
                                      __uint_as_float(*(u32*)&hc));
                bks[k] = b;
                rnk[k] = atomicAdd(&hist[b], 1u);
            }
        }
        __syncthreads();

        // exclusive scan of hist[0..BDIM): one entry per thread
        u32 s = hist[threadIdx.x];
        u32 inc = s;
        #pragma unroll
        for (int d = 1; d < 64; d <<= 1) {
            u32 v = __shfl_up(inc, d, 64);
            if (lane >= d) inc += v;
        }
        if (lane == 63) wsum[wid] = inc;
        __syncthreads();
        u32 woff = 0;
        for (int w = 0; w < wid; ++w) woff += wsum[w];
        lbase[threadIdx.x] = woff + inc - s;
        __syncthreads();

        // bucket-sorted scatter into LDS
        #pragma unroll
        for (int k = 0; k < KPC; ++k) {
            if (val[k]) {
                u32 p = lbase[bks[k]] + rnk[k];
                buf[p] = recs[k];
                bkt[p] = (u16)bks[k];
            }
        }
        __syncthreads();

        // coalesced flush: consecutive j -> consecutive global addresses per run
        for (int j = threadIdx.x; j < cn; j += 256) {
            u32 b = bkt[j];
            R[(size_t)gcur[b] + (u32)j - lbase[b]] = buf[j];
        }
        __syncthreads();

        // advance global cursors
        if (threadIdx.x < BDIM) gcur[threadIdx.x] += hist[threadIdx.x];
        __syncthreads();
    }
}

// edge pass 1: nt-stream R, fp16 kv gathers (L2-resident 4MB table), LDS accumulate
__global__ __launch_bounds__(CTH) void k_attn16(
    const float4* __restrict__ R,
    const u32* __restrict__ bucketBase, const u32* __restrict__ bucketTotal,
    const uint2* __restrict__ kvh, const float2* __restrict__ qp,
    const float* __restrict__ x,
    const float* __restrict__ Wskip, const float* __restrict__ bskip,
    float2* __restrict__ h, float* __restrict__ accum) {
    __shared__ float sA[BSZ], m0A[BSZ], m1A[BSZ];
    __shared__ float2 qT[BSZ];
    int b = blockIdx.x, base = b << BSH;
    for (int j = threadIdx.x; j < BSZ; j += CTH) {
        sA[j] = 0.f; m0A[j] = 0.f; m1A[j] = 0.f;
        int i = base + j;
        qT[j] = (i < NNODES) ? qp[i] : make_float2(0.f, 0.f);
    }
    __syncthreads();
    int beg = bucketBase[b], end = beg + bucketTotal[b];
    int idx = beg + threadIdx.x;
    for (; idx + 3 * CTH < end; idx += 4 * CTH) {
        float4 r[4];
        #pragma unroll
        for (int u = 0; u < 4; ++u) r[u] = ntload4(&R[idx + u * CTH]);
        int li[4]; uint2 kvv[4];
        #pragma unroll
        for (int u = 0; u < 4; ++u) {
            u32 rec = __float_as_uint(r[u].x);
            li[u] = rec >> 19;
            kvv[u] = kvh[rec & 0x7FFFFu];
        }
        #pragma unroll
        for (int u = 0; u < 4; ++u) {
            float2 kf = __half22float2(*(__half2*)&kvv[u].x);
            float2 vf = __half22float2(*(__half2*)&kvv[u].y);
            float2 qv = qT[li[u]];
            float alpha = fmaf(qv.x, kf.x + r[u].y, qv.y * (kf.y + r[u].z)) * 0.70710678118654752f;
            float a = __expf(alpha);
            atomicAdd(&sA[li[u]], a);
            atomicAdd(&m0A[li[u]], a * (vf.x + r[u].y));
            atomicAdd(&m1A[li[u]], a * (vf.y + r[u].z));
        }
    }
    for (; idx < end; idx += CTH) {
        float4 r = ntload4(&R[idx]);
        u32 rec = __float_as_uint(r.x);
        int li = rec >> 19;
        uint2 kvv = kvh[rec & 0x7FFFFu];
        float2 kf = __half22float2(*(__half2*)&kvv.x);
        float2 vf = __half22float2(*(__half2*)&kvv.y);
        float2 qv = qT[li];
        float alpha = fmaf(qv.x, kf.x + r.y, qv.y * (kf.y + r.z)) * 0.70710678118654752f;
        float a = __expf(alpha);
        atomicAdd(&sA[li], a);
        atomicAdd(&m0A[li], a * (vf.x + r.y));
        atomicAdd(&m1A[li], a * (vf.y + r.z));
    }
    __syncthreads();
    float r0 = 0.f, r1 = 0.f, r2 = 0.f, r3 = 0.f;
    float w00 = Wskip[0], w01 = Wskip[1], w10 = Wskip[2], w11 = Wskip[3];
    float c0 = bskip[0], c1 = bskip[1];
    for (int j = threadIdx.x; j < BSZ; j += CTH) {
        int i = base + j;
        if (i < NNODES) {
            float2 xv = ((const float2*)x)[i];
            float s = sA[j];
            float inv = s > 0.f ? 1.f / s : 0.f;
            float h0 = fmaf(m0A[j], inv, fmaf(w00, xv.x, fmaf(w01, xv.y, c0)));
            float h1 = fmaf(m1A[j], inv, fmaf(w10, xv.x, fmaf(w11, xv.y, c1)));
            h[i] = make_float2(h0, h1);
            r0 += h0; r1 += h1; r2 += h0 * h0; r3 += h1 * h1;
        }
    }
    block_reduce_atomic4_w16(r0, r1, r2, r3, accum);
}

// edge pass 2: nt-stream R, per-bucket LDS max (skip masked dst), fused final output
__global__ __launch_bounds__(CTH) void k_nmax16(
    const float4* __restrict__ R,
    const u32* __restrict__ bucketBase, const u32* __restrict__ bucketTotal,
    const float2* __restrict__ pp, const float* __restrict__ accum,
    const float* __restrict__ Wf, const float* __restrict__ bf,
    const float* __restrict__ mask, float* __restrict__ out) {
    __shared__ u32 mxA[BSZ];
    __shared__ float maskT[BSZ];
    int b = blockIdx.x, base = b << BSH;
    for (int j = threadIdx.x; j < BSZ; j += CTH) {
        mxA[j] = 0u;
        int i = base + j;
        maskT[j] = (i < NNODES) ? mask[i] : 0.f;
    }
    __syncthreads();
    float inv0 = accum[12], inv1 = accum[13];
    int beg = bucketBase[b], end = beg + bucketTotal[b];
    int idx = beg + threadIdx.x;
    for (; idx + 3 * CTH < end; idx += 4 * CTH) {
        float4 r[4];
        #pragma unroll
        for (int u = 0; u < 4; ++u) r[u] = ntload4(&R[idx + u * CTH]);
        #pragma unroll
        for (int u = 0; u < 4; ++u) {
            u32 rec = __float_as_uint(r[u].x);
            int li = rec >> 19;
            if (maskT[li] == 0.f) continue;
            int si = rec & 0x7FFFFu;
            u32 hcbits = __float_as_uint(r[u].w);
            __half2 hc = *(__half2*)&hcbits;
            float2 cf = __half22float2(hc);
            float2 pv = pp[si];
            float sE = fmaf(pv.x * inv0, cf.x, pv.y * inv1 * cf.y);
            atomicMax(&mxA[li], fmap_ord(sE));
        }
    }
    for (; idx < end; idx += CTH) {
        float4 r = ntload4(&R[idx]);
        u32 rec = __float_as_uint(r.x);
        int li = rec >> 19;
        if (maskT[li] == 0.f) continue;
        int si = rec & 0x7FFFFu;
        u32 hcbits = __float_as_uint(r.w);
        __half2 hc = *(__half2*)&hcbits;
        float2 cf = __half22float2(hc);
        float2 pv = pp[si];
        float sE = fmaf(pv.x * inv0, cf.x, pv.y * inv1 * cf.y);
        atomicMax(&mxA[li], fmap_ord(sE));
    }
    __syncthreads();
    float wf0 = Wf[0], wf1 = Wf[1], bb = bf[0];
    for (int j = threadIdx.x; j < BSZ; j += CTH) {
        int i = base + j;
        if (i >= NNODES) continue;
        u32 m = mxA[j];   // 0 <=> no relevant edge; masked nodes output 0 anyway
        float h0, h1;
        if (m != 0u) { float v = funmap_ord(m); h0 = v; h1 = 1.f - v; }
        else { float2 pv = pp[i]; h0 = pv.x * inv0; h1 = pv.y * inv1; }
        out[i] = fmaf(wf0, h0, fmaf(wf1, h1, bb)) * maskT[j];
    }
}

// ---------------- fallback (round-2 proven, device-scope atomics) ----------------

__global__ __launch_bounds__(256) void k_init_f(float* s, float* msg, u32* mxb, float* accum) {
    int i = blockIdx.x * blockDim.x + threadIdx.x;
    if (i < NNODES) { s[i] = 0.f; mxb[i] = 0u; }
    if (i < 2 * NNODES) msg[i] = 0.f;
    if (i < 16) accum[i] = 0.f;
}

__global__ __launch_bounds__(256) void k_node_prep_f(
    const float* __restrict__ x,
    const float* __restrict__ Wq, const float* __restrict__ bq,
    const float* __restrict__ Wk, const float* __restrict__ bk,
    const float* __restrict__ Wv, const float* __restrict__ bv,
    float2* __restrict__ q, float4* __restrict__ kv) {
    int i = blockIdx.x * blockDim.x + threadIdx.x;
    if (i >= NNODES) return;
    float2 xv = ((const float2*)x)[i];
    float q0 = fmaf(Wq[0], xv.x, fmaf(Wq[1], xv.y, bq[0]));
    float q1 = fmaf(Wq[2], xv.x, fmaf(Wq[3], xv.y, bq[1]));
    float k0 = fmaf(Wk[0], xv.x, fmaf(Wk[1], xv.y, bk[0]));
    float k1 = fmaf(Wk[2], xv.x, fmaf(Wk[3], xv.y, bk[1]));
    float v0 = fmaf(Wv[0], xv.x, fmaf(Wv[1], xv.y, bv[0]));
    float v1 = fmaf(Wv[2], xv.x, fmaf(Wv[3], xv.y, bv[1]));
    q[i] = make_float2(q0, q1);
    kv[i] = make_float4(k0, k1, v0, v1);
}

__global__ __launch_bounds__(256) void k_edge_attn_f(
    const int* __restrict__ ei, const float* __restrict__ ea,
    const float* __restrict__ We,
    const float2* __restrict__ q, const float4* __restrict__ kv,
    float* __restrict__ s, float* __restrict__ msg) {
    int e = blockIdx.x * blockDim.x + threadIdx.x;
    if (e >= NEDGES) return;
    float we00 = We[0], we01 = We[1], we10 = We[2], we11 = We[3];
    int si = ((const int2*)ei)[e].y;
    int di = ((const int2*)(ei + 2 * NEDGES))[e].y;
    float2 eav = ((const float2*)ea)[2 * e + 1];
    float4 kvv = kv[si];
    float2 qv = q[di];
    float e0 = fmaf(we00, eav.x, we01 * eav.y);
    float e1 = fmaf(we10, eav.x, we11 * eav.y);
    float alpha = fmaf(qv.x, kvv.x + e0, qv.y * (kvv.y + e1)) * 0.70710678118654752f;
    float a = __expf(alpha);
    unsafeAtomicAdd(&s[di], a);
    unsafeAtomicAdd(&msg[2 * di], a * (kvv.z + e0));
    unsafeAtomicAdd(&msg[2 * di + 1], a * (kvv.w + e1));
}

__global__ __launch_bounds__(256) void k_node_h_f(
    const float* __restrict__ x,
    const float* __restrict__ Wskip, const float* __restrict__ bskip,
    const float* __restrict__ s, float* __restrict__ msg, float* __restrict__ accum) {
    int i = blockIdx.x * blockDim.x + threadIdx.x;
    float h0 = 0.f, h1 = 0.f;
    if (i < NNODES) {
        float2 xv = ((const float2*)x)[i];
        float sk0 = fmaf(Wskip[0], xv.x, fmaf(Wskip[1], xv.y, bskip[0]));
        float sk1 = fmaf(Wskip[2], xv.x, fmaf(Wskip[3], xv.y, bskip[1]));
        float sv = s[i];
        float inv = sv > 0.f ? 1.f / sv : 0.f;
        h0 = fmaf(msg[2 * i], inv, sk0);
        h1 = fmaf(msg[2 * i + 1], inv, sk1);
        msg[2 * i] = h0;
        msg[2 * i + 1] = h1;
    }
    block_reduce_atomic4(h0, h1, h0 * h0, h1 * h1, accum);
}

__global__ __launch_bounds__(256) void k_edge_nmax_f(
    const int* __restrict__ ei, const float* __restrict__ ea,
    const float2* __restrict__ pp, const float* __restrict__ accum,
    u32* __restrict__ mxb) {
    int e = blockIdx.x * blockDim.x + threadIdx.x;
    if (e >= NEDGES) return;
    float inv0 = accum[12], inv1 = accum[13];
    int si = ((const int2*)ei)[e].y;
    int di = ((const int2*)(ei + 2 * NEDGES))[e].y;
    float2 c = ((const float2*)ea)[2 * e];
    float2 pv = pp[si];
    float sE = fmaf(pv.x * inv0, c.x, pv.y * inv1 * c.y);
    atomicMax(&mxb[di], fmap_ord(sE));
}

__global__ __launch_bounds__(256) void k_final_f(
    const u32* __restrict__ mxb, const float2* __restrict__ pp,
    const float* __restrict__ accum,
    const float* __restrict__ Wf, const float* __restrict__ bf,
    const float* __restrict__ mask, float* __restrict__ out) {
    int i = blockIdx.x * blockDim.x + threadIdx.x;
    if (i >= NNODES) return;
    u32 m = mxb[i];
    float h0, h1;
    if (m != 0u) {
        float v = funmap_ord(m);
        h0 = v;
        h1 = 1.f - v;
    } else {
        float2 pv = pp[i];
        h0 = pv.x * accum[12];
        h1 = pv.y * accum[13];
    }
    out[i] = fmaf(Wf[0], h0, fmaf(Wf[1], h1, bf[0])) * mask[i];
}

// ---------------- launch ----------------

extern "C" void kernel_launch(void* const* d_in, const int* in_sizes, int n_in,
                              void* d_out, int out_size, void* d_ws, size_t ws_size,
                              hipStream_t stream) {
    const float* x     = (const float*)d_in[0];
    const int*   ei    = (const int*)d_in[1];
    const float* ea    = (const float*)d_in[2];
    const float* mask  = (const float*)d_in[3];
    const float* Wq    = (const float*)d_in[4];
    const float* bq    = (const float*)d_in[5];
    const float* Wk    = (const float*)d_in[6];
    const float* bk    = (const float*)d_in[7];
    const float* Wv    = (const float*)d_in[8];
    const float* bv    = (const float*)d_in[9];
    const float* We    = (const float*)d_in[10];
    const float* Wskip = (const float*)d_in[11];
    const float* bskip = (const float*)d_in[12];
    const float* gamma = (const float*)d_in[13];
    const float* beta  = (const float*)d_in[14];
    const float* Wf    = (const float*)d_in[15];
    const float* bf    = (const float*)d_in[16];
    float* out = (float*)d_out;

    const size_t N = NNODES;
    const size_t E = NEDGES;
    const int B = 256;
    const int gridN = (NNODES + B - 1) / B;

    const int2*   src2 = (const int2*)ei;
    const int2*   dst2 = (const int2*)(ei + 2 * NEDGES);
    const float4* ea4  = (const float4*)ea;

    size_t need16 = 8 * N             // kvh uint2 (fp16x4)
                  + 16 * E            // R records (1 x float4)
                  + 8 * N             // q
                  + 8 * N             // h
                  + 8 * N             // p
                  + 4 * (size_t)NBLK * BDIM
                  + 4 * BDIM
                  + 4 * (BDIM + 16)
                  + 64;

    if (ws_size >= need16) {
        char* base = (char*)d_ws;
        uint2*  kvh = (uint2*)base;                 base += 8 * N;
        float4* R  = (float4*)base;                 base += 16 * E;
        float2* q  = (float2*)base;                 base += 8 * N;
        float2* h  = (float2*)base;                 base += 8 * N;
        float2* p  = (float2*)base;                 base += 8 * N;
        u32*    M  = (u32*)base;                    base += 4 * (size_t)NBLK * BDIM;
        u32*    bT = (u32*)base;                    base += 4 * BDIM;
        u32*    bB = (u32*)base;                    base += 4 * (BDIM + 16);
        float*  accum = (float*)base;

        k_zero_accum<<<1, 64, 0, stream>>>(accum);
        k_node_prep<<<gridN, B, 0, stream>>>(x, Wq, bq, Wk, bk, Wv, bv, q, kvh);
        k_hist<<<NBLK, B, 0, stream>>>(dst2, M);
        k_bucket_prefix<<<BDIM, B, 0, stream>>>(M, bT);
        k_scan_serial<<<1, B, 0, stream>>>(bT, bB);
        k_scatter_stg<<<NBLK, B, 0, stream>>>(src2, dst2, ea4, We, M, bB, R);
        k_attn16<<<NBKT, CTH, 0, stream>>>(R, bB, bT, kvh, q, x, Wskip, bskip, h, accum);
        k_ln_final<<<1, 1, 0, stream>>>(gamma, beta, accum);
        k_softmax<<<gridN, B, 0, stream>>>(h, p, accum);
        k_sm_final<<<1, 1, 0, stream>>>(accum);
        k_nmax16<<<NBKT, CTH, 0, stream>>>(R, bB, bT, p, accum, Wf, bf, mask, out);
    } else {
        float*  q   = (float*)d_ws;
        float*  kvf = q + 2 * N;
        float*  s   = kvf + 4 * N;
        float*  msg = s + N;
        u32*    mxb = (u32*)(msg + 2 * N);
        float*  accum = (float*)(mxb + N);
        int grid2N = (int)((2 * N + B - 1) / B);
        int gridE  = (NEDGES + B - 1) / B;

        k_init_f<<<grid2N, B, 0, stream>>>(s, msg, mxb, accum);
        k_node_prep_f<<<gridN, B, 0, stream>>>(x, Wq, bq, Wk, bk, Wv, bv, (float2*)q, (float4*)kvf);
        k_edge_attn_f<<<gridE, B, 0, stream>>>(ei, ea, We, (const float2*)q, (const float4*)kvf, s, msg);
        k_node_h_f<<<gridN, B, 0, stream>>>(x, Wskip, bskip, s, msg, accum);
        k_ln_final<<<1, 1, 0, stream>>>(gamma, beta, accum);
        k_softmax<<<gridN, B, 0, stream>>>((const float2*)msg, (float2*)q, accum);
        k_sm_final<<<1, 1, 0, stream>>>(accum);
        k_edge_nmax_f<<<gridE, B, 0, stream>>>(ei, ea, (const float2*)q, accum, mxb);
        k_final_f<<<gridN, B, 0, stream>>>(mxb, (const float2*)q, accum, Wf, bf, mask, out);
    }
}